// Round 1
// baseline (262.538 us; speedup 1.0000x reference)
//
#include <hip/hip_runtime.h>
#include <stdint.h>

#define BB 2
#define TT 2048
#define CC 1024
#define HH 16
#define DD 64
#define MM (BB*TT)   // 4096

typedef unsigned short u16;
typedef __attribute__((ext_vector_type(8))) short short8;
typedef __attribute__((ext_vector_type(4))) float float4v;
typedef __attribute__((ext_vector_type(4))) unsigned short ushort4v;

typedef const __attribute__((address_space(1))) void* gas_t;
typedef __attribute__((address_space(3))) void* las_t;

__device__ __forceinline__ u16 f2bf(float f) {
  union { float f; uint32_t u; } v; v.f = f;
  uint32_t u = v.u;
  return (u16)((u + 0x7FFFu + ((u >> 16) & 1)) >> 16);
}

__device__ __forceinline__ void gld_lds16(const void* g, void* l) {
  __builtin_amdgcn_global_load_lds((gas_t)g, (las_t)l, 16, 0, 0);
}

// ---------------- convert x (fp32 -> bf16) ----------------
__global__ __launch_bounds__(256) void k_convert_x(const float* __restrict__ x, u16* __restrict__ xb) {
  int i = (blockIdx.x * 256 + threadIdx.x) * 4;
  float4v v = *(const float4v*)(x + i);
  ushort4v o;
  o[0] = f2bf(v[0]); o[1] = f2bf(v[1]); o[2] = f2bf(v[2]); o[3] = f2bf(v[3]);
  *(ushort4v*)(xb + i) = o;
}

// ---------------- transpose weights (fp32 [k][n] -> bf16 [n][k]) ----------------
__global__ __launch_bounds__(256) void k_transpose_w(const float* __restrict__ Wq, const float* __restrict__ Wk,
                                                     const float* __restrict__ Wv, const float* __restrict__ Wo,
                                                     u16* __restrict__ WT) {
  __shared__ u16 tile[64][72];
  int which = blockIdx.y;
  const float* W = (which == 0) ? Wq : (which == 1) ? Wk : (which == 2) ? Wv : Wo;
  u16* out = WT + (size_t)which * CC * CC;
  int tr = (blockIdx.x >> 4) * 64, tc = (blockIdx.x & 15) * 64;
#pragma unroll
  for (int i = 0; i < 16; ++i) {
    int e = i * 256 + threadIdx.x;
    int r = e >> 6, c = e & 63;
    tile[r][c] = f2bf(W[(size_t)(tr + r) * CC + tc + c]);
  }
  __syncthreads();
#pragma unroll
  for (int i = 0; i < 16; ++i) {
    int e = i * 256 + threadIdx.x;
    int cc2 = e >> 6, rr = e & 63;
    out[(size_t)(tc + cc2) * CC + tr + rr] = tile[rr][cc2];
  }
}

// ---------------- QKV projection GEMM ----------------
// Y = xb[4096,1024] @ W + b ; writes Q/K as bf16 [b,h,t,d] (Q pre-scaled), V as bf16 [b,h,d,t]
__global__ __launch_bounds__(256, 2) void k_qkv_gemm(
    const u16* __restrict__ xb, const u16* __restrict__ WTall,
    const float* __restrict__ bq, const float* __restrict__ bk, const float* __restrict__ bv,
    u16* __restrict__ Qw, u16* __restrict__ Kw, u16* __restrict__ Vtw) {
  __shared__ u16 Al[2][128 * 32];
  __shared__ u16 Bl[2][128 * 32];
  int p = blockIdx.y;
  const u16* WT = WTall + (size_t)p * (CC * CC);
  const float* bias = (p == 0) ? bq : (p == 1) ? bk : bv;
  int m0 = (blockIdx.x >> 3) * 128;
  int n0 = (blockIdx.x & 7) * 128;
  int tid = threadIdx.x;
  int lane = tid & 63, wave = tid >> 6;
  int wr = wave >> 1, wc = wave & 1;

  float4v acc[4][4];
#pragma unroll
  for (int i = 0; i < 4; ++i)
#pragma unroll
    for (int j = 0; j < 4; ++j) acc[i][j] = float4v{0.f, 0.f, 0.f, 0.f};

  auto stage = [&](int buf, int kt) {
    int k0 = kt * 32;
#pragma unroll
    for (int it = 0; it < 2; ++it) {
      int fc = tid + it * 256;
      int r = fc >> 2, c = fc & 3;
      int cg = c ^ ((r >> 1) & 3);
      const u16* gA = xb + (size_t)(m0 + r) * CC + k0 + cg * 8;
      const u16* gB = WT + (size_t)(n0 + r) * CC + k0 + cg * 8;
      char* lA = (char*)&Al[buf][0] + (wave * 64 + it * 256) * 16;
      char* lB = (char*)&Bl[buf][0] + (wave * 64 + it * 256) * 16;
      gld_lds16(gA, lA);
      gld_lds16(gB, lB);
    }
  };

  stage(0, 0);
  __syncthreads();
  int buf = 0;
  for (int kt = 0; kt < 32; ++kt) {
    if (kt + 1 < 32) stage(buf ^ 1, kt + 1);
    short8 af[4], bfr[4];
#pragma unroll
    for (int mf = 0; mf < 4; ++mf) {
      int row = wr * 64 + mf * 16 + (lane & 15);
      int cs = (lane >> 4) ^ ((row >> 1) & 3);
      af[mf] = *(const short8*)((const char*)&Al[buf][0] + row * 64 + cs * 16);
    }
#pragma unroll
    for (int nf = 0; nf < 4; ++nf) {
      int row = wc * 64 + nf * 16 + (lane & 15);
      int cs = (lane >> 4) ^ ((row >> 1) & 3);
      bfr[nf] = *(const short8*)((const char*)&Bl[buf][0] + row * 64 + cs * 16);
    }
#pragma unroll
    for (int mf = 0; mf < 4; ++mf)
#pragma unroll
      for (int nf = 0; nf < 4; ++nf)
        acc[mf][nf] = __builtin_amdgcn_mfma_f32_16x16x32_bf16(af[mf], bfr[nf], acc[mf][nf], 0, 0, 0);
    __syncthreads();
    buf ^= 1;
  }

  // epilogue: Q scaled by 1/sqrt(d) * log2(e) so attention can use exp2
  const float QSCALE = 0.125f * 1.44269504088896340736f;
#pragma unroll
  for (int mf = 0; mf < 4; ++mf) {
#pragma unroll
    for (int nf = 0; nf < 4; ++nf) {
      int n = n0 + wc * 64 + nf * 16 + (lane & 15);
      float bval = bias[n];
      int rowBase = wr * 64 + mf * 16 + (lane >> 4) * 4;
      int m_ = m0 + rowBase;
      int b_ = m_ >> 11, t_ = m_ & 2047;
      int h_ = n >> 6, dd = n & 63;
      if (p == 2) {
        ushort4v pk;
#pragma unroll
        for (int i = 0; i < 4; ++i) pk[i] = f2bf(acc[mf][nf][i] + bval);
        *(ushort4v*)(Vtw + ((size_t)(b_ * HH + h_) * DD + dd) * TT + t_) = pk;
      } else {
        u16* outp = (p == 0) ? Qw : Kw;
        float s = (p == 0) ? QSCALE : 1.0f;
#pragma unroll
        for (int i = 0; i < 4; ++i) {
          outp[((size_t)(b_ * HH + h_) * TT + (t_ + i)) * DD + dd] = f2bf((acc[mf][nf][i] + bval) * s);
        }
      }
    }
  }
}

// ---------------- flash attention (causal) ----------------
__global__ __launch_bounds__(256, 2) void k_attn(
    const u16* __restrict__ Qw, const u16* __restrict__ Kw,
    const u16* __restrict__ Vtw, u16* __restrict__ Ow) {
  __shared__ u16 Kl[2][64 * 64];
  __shared__ u16 Vl[2][64 * 64];
  __shared__ u16 Pl[4][32 * 88];
  int bh = blockIdx.y;
  int q0 = blockIdx.x * 128;
  int tid = threadIdx.x, lane = tid & 63, wave = tid >> 6;
  int qw = q0 + wave * 32;
  const u16* Qbase = Qw + (size_t)bh * TT * DD;
  const u16* Kbase = Kw + (size_t)bh * TT * DD;
  const u16* Vbase = Vtw + (size_t)bh * DD * TT;

  short8 qf[2][2];
#pragma unroll
  for (int mf = 0; mf < 2; ++mf)
#pragma unroll
    for (int kc = 0; kc < 2; ++kc)
      qf[mf][kc] = *(const short8*)(Qbase + (size_t)(qw + mf * 16 + (lane & 15)) * DD + kc * 32 + (lane >> 4) * 8);

  float4v accd[2][4];
  float mrun[2][4], lrun[2][4];
#pragma unroll
  for (int mf = 0; mf < 2; ++mf) {
#pragma unroll
    for (int nf = 0; nf < 4; ++nf) accd[mf][nf] = float4v{0.f, 0.f, 0.f, 0.f};
#pragma unroll
    for (int i = 0; i < 4; ++i) { mrun[mf][i] = -1e30f; lrun[mf][i] = 0.f; }
  }

  int nt = q0 / 64 + 2;
  auto stage = [&](int buf, int t) {
    int kv0 = t * 64;
#pragma unroll
    for (int it = 0; it < 2; ++it) {
      int fc = tid + it * 256;
      int r = fc >> 3, c = fc & 7;
      int cg = c ^ (r & 7);
      const u16* gK = Kbase + (size_t)(kv0 + r) * DD + cg * 8;
      const u16* gV = Vbase + (size_t)r * TT + kv0 + cg * 8;
      char* lK = (char*)&Kl[buf][0] + (wave * 64 + it * 256) * 16;
      char* lV = (char*)&Vl[buf][0] + (wave * 64 + it * 256) * 16;
      gld_lds16(gK, lK);
      gld_lds16(gV, lV);
    }
  };

  stage(0, 0);
  __syncthreads();
  int buf = 0;
  for (int t = 0; t < nt; ++t) {
    if (t + 1 < nt) stage(buf ^ 1, t + 1);
    int kv0 = t * 64;
    bool skip = kv0 > qw + 31;
    if (!skip) {
      bool diag = (kv0 + 63) > qw;
      float4v s[2][4];
#pragma unroll
      for (int mf = 0; mf < 2; ++mf)
#pragma unroll
        for (int nf = 0; nf < 4; ++nf) s[mf][nf] = float4v{0.f, 0.f, 0.f, 0.f};
#pragma unroll
      for (int kc = 0; kc < 2; ++kc) {
        short8 kf[4];
#pragma unroll
        for (int nf = 0; nf < 4; ++nf) {
          int row = nf * 16 + (lane & 15);
          int cs = (kc * 4 + (lane >> 4)) ^ (row & 7);
          kf[nf] = *(const short8*)((const char*)&Kl[buf][0] + row * 128 + cs * 16);
        }
#pragma unroll
        for (int mf = 0; mf < 2; ++mf)
#pragma unroll
          for (int nf = 0; nf < 4; ++nf)
            s[mf][nf] = __builtin_amdgcn_mfma_f32_16x16x32_bf16(qf[mf][kc], kf[nf], s[mf][nf], 0, 0, 0);
      }
      if (diag) {
#pragma unroll
        for (int mf = 0; mf < 2; ++mf)
#pragma unroll
          for (int nf = 0; nf < 4; ++nf)
#pragma unroll
            for (int i = 0; i < 4; ++i) {
              int qg = qw + mf * 16 + (lane >> 4) * 4 + i;
              int kg = kv0 + nf * 16 + (lane & 15);
              if (kg > qg) s[mf][nf][i] = -1e30f;
            }
      }
      // online softmax
#pragma unroll
      for (int mf = 0; mf < 2; ++mf) {
#pragma unroll
        for (int i = 0; i < 4; ++i) {
          float v = fmaxf(fmaxf(s[mf][0][i], s[mf][1][i]), fmaxf(s[mf][2][i], s[mf][3][i]));
          v = fmaxf(v, __shfl_xor(v, 1));
          v = fmaxf(v, __shfl_xor(v, 2));
          v = fmaxf(v, __shfl_xor(v, 4));
          v = fmaxf(v, __shfl_xor(v, 8));
          float mn = fmaxf(mrun[mf][i], v);
          float sc = __builtin_exp2f(mrun[mf][i] - mn);
          mrun[mf][i] = mn;
          lrun[mf][i] *= sc;
#pragma unroll
          for (int nf = 0; nf < 4; ++nf) accd[mf][nf][i] *= sc;
        }
      }
      // P = exp2(S - m), write to LDS, accumulate row sums
#pragma unroll
      for (int mf = 0; mf < 2; ++mf) {
        float rs[4] = {0.f, 0.f, 0.f, 0.f};
#pragma unroll
        for (int nf = 0; nf < 4; ++nf)
#pragma unroll
          for (int i = 0; i < 4; ++i) {
            float pv = __builtin_exp2f(s[mf][nf][i] - mrun[mf][i]);
            rs[i] += pv;
            Pl[wave][(mf * 16 + (lane >> 4) * 4 + i) * 88 + nf * 16 + (lane & 15)] = f2bf(pv);
          }
#pragma unroll
        for (int i = 0; i < 4; ++i) {
          float r = rs[i];
          r += __shfl_xor(r, 1);
          r += __shfl_xor(r, 2);
          r += __shfl_xor(r, 4);
          r += __shfl_xor(r, 8);
          lrun[mf][i] += r;
        }
      }
      // PV
#pragma unroll
      for (int kc = 0; kc < 2; ++kc) {
        short8 pf[2], vf[4];
#pragma unroll
        for (int mf = 0; mf < 2; ++mf)
          pf[mf] = *(const short8*)((const char*)&Pl[wave][0] + (mf * 16 + (lane & 15)) * 176 + kc * 64 + (lane >> 4) * 16);
#pragma unroll
        for (int nf = 0; nf < 4; ++nf) {
          int row = nf * 16 + (lane & 15);
          int cs = (kc * 4 + (lane >> 4)) ^ (row & 7);
          vf[nf] = *(const short8*)((const char*)&Vl[buf][0] + row * 128 + cs * 16);
        }
#pragma unroll
        for (int mf = 0; mf < 2; ++mf)
#pragma unroll
          for (int nf = 0; nf < 4; ++nf)
            accd[mf][nf] = __builtin_amdgcn_mfma_f32_16x16x32_bf16(pf[mf], vf[nf], accd[mf][nf], 0, 0, 0);
      }
    }
    __syncthreads();
    buf ^= 1;
  }

  int b_ = bh >> 4, h_ = bh & 15;
#pragma unroll
  for (int mf = 0; mf < 2; ++mf)
#pragma unroll
    for (int i = 0; i < 4; ++i) {
      float inv = 1.f / lrun[mf][i];
      int t_ = qw + mf * 16 + (lane >> 4) * 4 + i;
#pragma unroll
      for (int nf = 0; nf < 4; ++nf) {
        int dd = nf * 16 + (lane & 15);
        Ow[((size_t)(b_ * TT + t_)) * CC + h_ * DD + dd] = f2bf(accd[mf][nf][i] * inv);
      }
    }
}

// ---------------- output projection GEMM (bf16 in, fp32 out) ----------------
__global__ __launch_bounds__(256, 2) void k_out_gemm(
    const u16* __restrict__ Ob, const u16* __restrict__ WoT,
    const float* __restrict__ bo, float* __restrict__ out) {
  __shared__ u16 Al[2][128 * 32];
  __shared__ u16 Bl[2][128 * 32];
  int m0 = (blockIdx.x >> 3) * 128;
  int n0 = (blockIdx.x & 7) * 128;
  int tid = threadIdx.x;
  int lane = tid & 63, wave = tid >> 6;
  int wr = wave >> 1, wc = wave & 1;

  float4v acc[4][4];
#pragma unroll
  for (int i = 0; i < 4; ++i)
#pragma unroll
    for (int j = 0; j < 4; ++j) acc[i][j] = float4v{0.f, 0.f, 0.f, 0.f};

  auto stage = [&](int buf, int kt) {
    int k0 = kt * 32;
#pragma unroll
    for (int it = 0; it < 2; ++it) {
      int fc = tid + it * 256;
      int r = fc >> 2, c = fc & 3;
      int cg = c ^ ((r >> 1) & 3);
      const u16* gA = Ob + (size_t)(m0 + r) * CC + k0 + cg * 8;
      const u16* gB = WoT + (size_t)(n0 + r) * CC + k0 + cg * 8;
      char* lA = (char*)&Al[buf][0] + (wave * 64 + it * 256) * 16;
      char* lB = (char*)&Bl[buf][0] + (wave * 64 + it * 256) * 16;
      gld_lds16(gA, lA);
      gld_lds16(gB, lB);
    }
  };

  stage(0, 0);
  __syncthreads();
  int buf = 0;
  for (int kt = 0; kt < 32; ++kt) {
    if (kt + 1 < 32) stage(buf ^ 1, kt + 1);
    short8 af[4], bfr[4];
#pragma unroll
    for (int mf = 0; mf < 4; ++mf) {
      int row = wr * 64 + mf * 16 + (lane & 15);
      int cs = (lane >> 4) ^ ((row >> 1) & 3);
      af[mf] = *(const short8*)((const char*)&Al[buf][0] + row * 64 + cs * 16);
    }
#pragma unroll
    for (int nf = 0; nf < 4; ++nf) {
      int row = wc * 64 + nf * 16 + (lane & 15);
      int cs = (lane >> 4) ^ ((row >> 1) & 3);
      bfr[nf] = *(const short8*)((const char*)&Bl[buf][0] + row * 64 + cs * 16);
    }
#pragma unroll
    for (int mf = 0; mf < 4; ++mf)
#pragma unroll
      for (int nf = 0; nf < 4; ++nf)
        acc[mf][nf] = __builtin_amdgcn_mfma_f32_16x16x32_bf16(af[mf], bfr[nf], acc[mf][nf], 0, 0, 0);
    __syncthreads();
    buf ^= 1;
  }

#pragma unroll
  for (int mf = 0; mf < 4; ++mf)
#pragma unroll
    for (int nf = 0; nf < 4; ++nf) {
      int n = n0 + wc * 64 + nf * 16 + (lane & 15);
      float bval = bo[n];
      int rowBase = m0 + wr * 64 + mf * 16 + (lane >> 4) * 4;
#pragma unroll
      for (int i = 0; i < 4; ++i)
        out[(size_t)(rowBase + i) * CC + n] = acc[mf][nf][i] + bval;
    }
}

extern "C" void kernel_launch(void* const* d_in, const int* in_sizes, int n_in,
                              void* d_out, int out_size, void* d_ws, size_t ws_size,
                              hipStream_t stream) {
  const float* x  = (const float*)d_in[0];
  const float* Wq = (const float*)d_in[1];
  const float* bq = (const float*)d_in[2];
  const float* Wk = (const float*)d_in[3];
  const float* bk = (const float*)d_in[4];
  const float* Wv = (const float*)d_in[5];
  const float* bv = (const float*)d_in[6];
  const float* Wo = (const float*)d_in[7];
  const float* bo = (const float*)d_in[8];
  float* out = (float*)d_out;
  char* ws = (char*)d_ws;
  if (ws_size < (size_t)50331648) return;  // need 48 MB scratch

  u16* xb  = (u16*)(ws);                    // 8 MB
  u16* WT  = (u16*)(ws + 8388608);          // 4 x 2 MB (WqT,WkT,WvT,WoT)
  u16* Qw  = (u16*)(ws + 16777216);         // 8 MB  [b,h,t,d]
  u16* Kw  = (u16*)(ws + 25165824);         // 8 MB  [b,h,t,d]
  u16* Vtw = (u16*)(ws + 33554432);         // 8 MB  [b,h,d,t]
  u16* Ob  = (u16*)(ws + 41943040);         // 8 MB  [b*t, c]

  hipLaunchKernelGGL(k_convert_x, dim3(4096), dim3(256), 0, stream, x, xb);
  hipLaunchKernelGGL(k_transpose_w, dim3(256, 4), dim3(256), 0, stream, Wq, Wk, Wv, Wo, WT);
  hipLaunchKernelGGL(k_qkv_gemm, dim3(256, 3), dim3(256), 0, stream,
                     xb, WT, bq, bk, bv, Qw, Kw, Vtw);
  hipLaunchKernelGGL(k_attn, dim3(16, 32), dim3(256), 0, stream, Qw, Kw, Vtw, Ob);
  hipLaunchKernelGGL(k_out_gemm, dim3(256), dim3(256), 0, stream,
                     Ob, WT + 3 * 1048576, bo, out);
}